// Round 1
// 112.161 us; speedup vs baseline: 1.0182x; 1.0182x over previous
//
#include <hip/hip_runtime.h>
#include <math.h>

#define Bsz 8
#define Nsz 1024
#define FIN 128
#define Hh  4
#define FO  64
#define COLS 256   // Hh*FO
#define TN  16
#define TM  32
#define BN  (Bsz*Nsz)
#define XSTR 136   // ushort stride per m-row of proj x-tile (128 data + 8 pad)
#define PSTR 136   // ushort stride per r-row of p-tile (128 data + 8 pad -> 2-way banks)
#define LOG2E  1.44269504088896340f
#define CSHIFT 17.3123404906675611f   // 12*log2(e): exp(s-12) == exp2(s*log2e - CSHIFT)

typedef __attribute__((ext_vector_type(8))) short short8;
typedef __attribute__((ext_vector_type(4))) float f32x4;

static __device__ inline ushort f2bf(float f) {           // RNE float->bf16
    uint u = __float_as_uint(f);
    u += 0x7FFFu + ((u >> 16) & 1u);
    return (ushort)(u >> 16);
}
static __device__ inline float bf2f(ushort h) { return __uint_as_float(((uint)h) << 16); }

static __device__ inline float fexp2(float x) {
#if __has_builtin(__builtin_amdgcn_exp2f)
    return __builtin_amdgcn_exp2f(x);
#else
    float r; asm("v_exp_f32 %0, %1" : "=v"(r) : "v"(x));
    return r;
#endif
}

// ---------------- prep: Wt[n][k] = bf16(W[k][n]) ----------------
__global__ __launch_bounds__(256) void gat_prep(const float* __restrict__ W,
                                                ushort* __restrict__ Wt)
{
    const int g = blockIdx.x * 256 + threadIdx.x;   // 0..2047
    const int n = g >> 3, kc = (g & 7) * 16;
    ushort u[16];
    #pragma unroll
    for (int i = 0; i < 16; i++) u[i] = f2bf(W[(kc + i) * COLS + n]);
    int4* dst = (int4*)(Wt + n * FIN + kc);
    dst[0] = ((int4*)u)[0];
    dst[1] = ((int4*)u)[1];
}

// ---------------- Kernel A: h = x@W via MFMA; es/ed (pre-scaled by log2e) ----------------
__global__ __launch_bounds__(256) void gat_proj(
    const float* __restrict__ x, const ushort* __restrict__ Wt,
    const float* __restrict__ a, ushort* __restrict__ h_gB,
    float* __restrict__ es_g, float* __restrict__ ed_g)
{
    __shared__ ushort xs[16 * XSTR];   // 4.25 KB
    const int j    = threadIdx.x;
    const int w    = j >> 6, lane = j & 63, quad = lane >> 4, n16 = lane & 15;
    const int b    = blockIdx.x >> 6, mt16 = blockIdx.x & 63;
    const long rowbase = (long)b * Nsz + mt16 * 16;

    // B fragments from global Wt (L2-hot)
    short8 bfr[4][4];
    #pragma unroll
    for (int kk = 0; kk < 4; kk++)
        #pragma unroll
        for (int c4 = 0; c4 < 4; c4++)
            bfr[kk][c4] = *(const short8*)(Wt + (w*64 + c4*16 + n16) * FIN + kk*32 + quad*8);

    // stage x tile (16x128) as bf16 into LDS
    {
        const int r = j >> 4, k0 = (j & 15) * 8;
        const float4* g4 = (const float4*)(x + (rowbase + r) * FIN + k0);
        float4 v0 = g4[0], v1 = g4[1];
        ushort u[8] = { f2bf(v0.x), f2bf(v0.y), f2bf(v0.z), f2bf(v0.w),
                        f2bf(v1.x), f2bf(v1.y), f2bf(v1.z), f2bf(v1.w) };
        *(int4*)(xs + r * XSTR + k0) = *(int4*)u;
    }
    __syncthreads();

    f32x4 acc[4];
    #pragma unroll
    for (int c4 = 0; c4 < 4; c4++)
        #pragma unroll
        for (int r = 0; r < 4; r++) acc[c4][r] = 0.f;

    #pragma unroll
    for (int kk = 0; kk < 4; kk++) {
        short8 af = *(const short8*)(xs + n16 * XSTR + kk*32 + quad*8);
        #pragma unroll
        for (int c4 = 0; c4 < 4; c4++)
            acc[c4] = __builtin_amdgcn_mfma_f32_16x16x32_bf16(af, bfr[kk][c4], acc[c4], 0, 0, 0);
    }

    // ---- h_gB store: [b][mt=row/32][c][k=row%32] bf16 ----
    const int mtile = mt16 >> 1;
    const int kbase = (mt16 & 1) * 16 + quad * 4;
    #pragma unroll
    for (int c4 = 0; c4 < 4; c4++) {
        uint2 pk;
        pk.x = (uint)f2bf(acc[c4][0]) | ((uint)f2bf(acc[c4][1]) << 16);
        pk.y = (uint)f2bf(acc[c4][2]) | ((uint)f2bf(acc[c4][3]) << 16);
        const int c = w*64 + c4*16 + n16;
        *(uint2*)(h_gB + (((long)(b*32 + mtile) * COLS + c) * 32 + kbase)) = pk;
    }

    // ---- es/ed from fp32 accumulators (stored scaled by log2e for exp2-domain attn) ----
    float aS[4], aD[4];
    #pragma unroll
    for (int c4 = 0; c4 < 4; c4++) {
        aS[c4] = a[w * (2*FO) + c4*16 + n16];
        aD[c4] = a[w * (2*FO) + FO + c4*16 + n16];
    }
    #pragma unroll
    for (int reg = 0; reg < 4; reg++) {
        float ps = 0.f, pd = 0.f;
        #pragma unroll
        for (int c4 = 0; c4 < 4; c4++) {
            ps = fmaf(acc[c4][reg], aS[c4], ps);
            pd = fmaf(acc[c4][reg], aD[c4], pd);
        }
        #pragma unroll
        for (int off = 1; off < 16; off <<= 1) {
            ps += __shfl_xor(ps, off, 64);
            pd += __shfl_xor(pd, off, 64);
        }
        if (n16 == 0) {
            const long row = rowbase + quad*4 + reg;
            es_g[(long)w * BN + row] = ps * LOG2E;
            ed_g[(long)w * BN + row] = pd * LOG2E;
        }
    }
}

// ---------------- Kernel B: 512 thr, in-block m-split, no hT (B-frags direct from L2) ----
// grid (Bsz, Nsz/TN): blockIdx.x = b so each XCD owns one batch's 64 blocks (linear%8 == x)
// -> h_gB working set per XCD = 512 KB, L2-resident. Wave-group g handles m-tiles
// [16g, 16g+16); partial acc/l merge in the epilogue (valid: fixed-SHIFT softmax).
__global__ __launch_bounds__(512, 4) void gat_attn(
    const int* __restrict__ adj, const ushort* __restrict__ h_gB,
    const float* __restrict__ es_g, const float* __restrict__ ed_g,
    float* __restrict__ out)
{
    __shared__ ushort pT[2][2][TN * PSTR];    // [group][buf] 17.4 KB
    __shared__ float  o_lds[2][Hh][TN][FO];   // 32 KB
    __shared__ float  l_lds[2][TN][Hh];       // 512 B

    const int j    = threadIdx.x;
    const int g    = j >> 8;                  // m-split wave-group
    const int jg   = j & 255;
    const int w    = jg >> 6;                 // wave-in-group: head (A) / row-group (S)
    const int lane = jg & 63;
    const int quad = lane >> 4, n16 = lane & 15;
    const int head = quad;                    // S-phase head
    const int mi   = n16 * 2;                 // S-phase m-pair
    const int b    = blockIdx.x;
    const int n0   = blockIdx.y * TN;
    const long rowb = (long)b * Nsz + n0;
    const int t0   = g * 16;                  // first m-tile of this group

    float es4[4];
    #pragma unroll
    for (int r4 = 0; r4 < 4; r4++)
        es4[r4] = es_g[(long)head * BN + rowb + w*4 + r4];

    f32x4 acc[4];
    #pragma unroll
    for (int c4 = 0; c4 < 4; c4++)
        #pragma unroll
        for (int r = 0; r < 4; r++) acc[c4][r] = 0.f;

    float l_part[4] = {0.f, 0.f, 0.f, 0.f};

    int2   ar[4];
    float2 edv;
    short8 bregA[4], bregB[4];

#define PRE_SE(t) {                                                             \
    const int m0 = (t) * TM + mi;                                               \
    _Pragma("unroll")                                                           \
    for (int r4 = 0; r4 < 4; r4++)                                              \
        ar[r4] = *(const int2*)(adj + (rowb + w*4 + r4) * (long)Nsz + m0);      \
    edv = *(const float2*)(ed_g + (long)head * BN + (long)b * Nsz + m0); }

#define PRE_B(t, brg) {                                                         \
    const ushort* hb = h_gB + (long)(b * 32 + (t)) * (COLS * TM);               \
    _Pragma("unroll")                                                           \
    for (int c4 = 0; c4 < 4; c4++)                                              \
        brg[c4] = *(const short8*)(hb + (w*64 + c4*16 + n16) * TM + quad * 8); }

#define PHASE_S(nb) {                                                           \
    _Pragma("unroll")                                                           \
    for (int r4 = 0; r4 < 4; r4++) {                                            \
        float s0 = es4[r4] + edv.x, s1 = es4[r4] + edv.y;                       \
        float u0 = fmaxf(s0, 0.2f * s0) - CSHIFT;                               \
        float u1 = fmaxf(s1, 0.2f * s1) - CSHIFT;                               \
        float e0 = fexp2(u0), e1 = fexp2(u1);                                   \
        e0 = (ar[r4].x > 0) ? e0 : 0.f;                                         \
        e1 = (ar[r4].y > 0) ? e1 : 0.f;                                         \
        uint pk;                                                                \
        asm("v_cvt_pk_bf16_f32 %0, %1, %2" : "=v"(pk) : "v"(e0), "v"(e1));      \
        *(uint*)(&pT[g][nb][(w*4 + r4) * PSTR + head * TM + mi]) = pk;          \
        l_part[r4] += __uint_as_float(pk << 16)                                 \
                    + __uint_as_float(pk & 0xFFFF0000u); } }

#define PHASE_A(cb, brg) {                                                      \
    short8 af = *(const short8*)(&pT[g][cb][n16 * PSTR + w * TM + quad * 8]);   \
    _Pragma("unroll")                                                           \
    for (int c4 = 0; c4 < 4; c4++)                                              \
        acc[c4] = __builtin_amdgcn_mfma_f32_16x16x32_bf16(af, brg[c4], acc[c4], 0, 0, 0); }

    PRE_SE(t0);
    PRE_B(t0, bregA);
    PHASE_S(0);                               // p(tile 0) -> buf0
    PRE_SE(t0 + 1);
    PRE_B(t0 + 1, bregB);
    __syncthreads();

    for (int i = 0; i < 16; i += 2) {
        PHASE_S(1);                           // p(tile i+1) -> buf1
        if (i < 14) PRE_SE(t0 + i + 2);
        PHASE_A(0, bregA);                    // consume tile i
        if (i < 14) PRE_B(t0 + i + 2, bregA);
        __syncthreads();
        if (i < 14) PHASE_S(0);               // p(tile i+2) -> buf0
        if (i < 14) PRE_SE(t0 + i + 3);
        PHASE_A(1, bregB);                    // consume tile i+1
        if (i < 14) PRE_B(t0 + i + 3, bregB);
        __syncthreads();
    }

    // ---- epilogue: reduce l over 16 pair-lanes (same head), merge groups, normalize ----
    #pragma unroll
    for (int r4 = 0; r4 < 4; r4++) {
        float lp = l_part[r4];
        #pragma unroll
        for (int off = 1; off < 16; off <<= 1) lp += __shfl_xor(lp, off, 64);
        if (n16 == 0) l_lds[g][w*4 + r4][head] = lp;
    }
    __syncthreads();

    float rinv[4];
    #pragma unroll
    for (int reg = 0; reg < 4; reg++) {
        const int r = quad*4 + reg;
        rinv[reg] = 0.25f / (l_lds[0][r][w] + l_lds[1][r][w]);
    }
    #pragma unroll
    for (int c4 = 0; c4 < 4; c4++)
        #pragma unroll
        for (int reg = 0; reg < 4; reg++)
            o_lds[g][w][quad*4 + reg][c4*16 + n16] = acc[c4][reg] * rinv[reg];
    __syncthreads();

    {
        const int f2 = j & 63, rb = (j >> 6) & 7;
        #pragma unroll
        for (int i2 = 0; i2 < 2; i2++) {
            const int r = i2 * 8 + rb;
            float s = 0.f;
            #pragma unroll
            for (int gg = 0; gg < 2; gg++)
                #pragma unroll
                for (int ww = 0; ww < 4; ww++)
                    s += o_lds[gg][ww][r][f2];
            out[(rowb + r) * FO + f2] = s;
        }
    }
#undef PRE_SE
#undef PRE_B
#undef PHASE_S
#undef PHASE_A
}

extern "C" void kernel_launch(void* const* d_in, const int* in_sizes, int n_in,
                              void* d_out, int out_size, void* d_ws, size_t ws_size,
                              hipStream_t stream) {
    const float* x   = (const float*)d_in[0];   // (8,1024,128) f32
    const int*   adj = (const int*)d_in[1];     // (8,1024,1024) i32
    const float* W   = (const float*)d_in[2];   // (128,256) f32
    const float* a   = (const float*)d_in[3];   // (4,128) f32
    float* out = (float*)d_out;                 // (8,1024,64) f32

    // ws: Wt bf16 (64KB) | h_gB bf16 (4MB) | es (128KB) | ed (128KB)
    ushort* Wt   = (ushort*)d_ws;
    ushort* h_gB = Wt + (size_t)COLS * FIN;
    float*  es_g = (float*)(h_gB + (size_t)BN * COLS);
    float*  ed_g = es_g + (size_t)Hh * BN;

    gat_prep<<<dim3(8),            dim3(256), 0, stream>>>(W, Wt);
    gat_proj<<<dim3(Bsz*Nsz/16),   dim3(256), 0, stream>>>(x, Wt, a, h_gB, es_g, ed_g);
    gat_attn<<<dim3(Bsz, Nsz/TN),  dim3(512), 0, stream>>>(adj, h_gB, es_g, ed_g, out);
}

// Round 3
// 109.642 us; speedup vs baseline: 1.0416x; 1.0230x over previous
//
#include <hip/hip_runtime.h>
#include <math.h>

#define Bsz 8
#define Nsz 1024
#define FIN 128
#define Hh  4
#define FO  64
#define COLS 256   // Hh*FO
#define TN  16
#define TM  32
#define NT  (Nsz/TM)   // 32 m-tiles
#define BN  (Bsz*Nsz)
#define XSTR 136   // ushort stride per m-row of proj x-tile (128 data + 8 pad)
#define LOG2E  1.44269504088896340f
#define CSHIFT 17.3123404906675611f     // 12*log2(e): exp(s-12) == exp2(s*log2e - CSHIFT)
#define NEG08C (-0.8f * CSHIFT)         // leaky in t-domain: 0.2*sL*log2e - C == fma(0.2, t, -0.8C)

typedef __attribute__((ext_vector_type(8))) short short8;
typedef __attribute__((ext_vector_type(4))) float f32x4;

static __device__ inline ushort f2bf(float f) {           // RNE float->bf16
    uint u = __float_as_uint(f);
    u += 0x7FFFu + ((u >> 16) & 1u);
    return (ushort)(u >> 16);
}

static __device__ inline float fexp2(float x) {
#if __has_builtin(__builtin_amdgcn_exp2f)
    return __builtin_amdgcn_exp2f(x);
#else
    float r; asm("v_exp_f32 %0, %1" : "=v"(r) : "v"(x));
    return r;
#endif
}

// ---------------- prep: adj->bitmask (blocks 0..1023) and Wt transpose (blocks 1024..1031) ----
__global__ __launch_bounds__(256) void gat_prep(const float* __restrict__ W,
                                                ushort* __restrict__ Wt,
                                                const int* __restrict__ adj,
                                                uint* __restrict__ ab)
{
    if (blockIdx.x < 1024) {
        // thread g packs adj[g*32 .. g*32+31] into one uint (bit i = adj>0)
        const long g = (long)blockIdx.x * 256 + threadIdx.x;   // 0..262143
        const int4* src = (const int4*)(adj + g * 32);
        uint m = 0u;
        #pragma unroll
        for (int i = 0; i < 8; i++) {
            int4 v = src[i];
            m |= (v.x > 0 ? 1u : 0u) << (i*4);
            m |= (v.y > 0 ? 1u : 0u) << (i*4 + 1);
            m |= (v.z > 0 ? 1u : 0u) << (i*4 + 2);
            m |= (v.w > 0 ? 1u : 0u) << (i*4 + 3);
        }
        ab[g] = m;
    } else {
        const int g = (blockIdx.x - 1024) * 256 + threadIdx.x;   // 0..2047
        const int n = g >> 3, kc = (g & 7) * 16;
        ushort u[16];
        #pragma unroll
        for (int i = 0; i < 16; i++) u[i] = f2bf(W[(kc + i) * COLS + n]);
        int4* dst = (int4*)(Wt + n * FIN + kc);
        dst[0] = ((int4*)u)[0];
        dst[1] = ((int4*)u)[1];
    }
}

// ---------------- Kernel A: h = x@W via MFMA; es (log2e-scaled, -CSHIFT folded) / ed (log2e-scaled) ----
__global__ __launch_bounds__(256) void gat_proj(
    const float* __restrict__ x, const ushort* __restrict__ Wt,
    const float* __restrict__ a, ushort* __restrict__ h_gB,
    float* __restrict__ es_g, float* __restrict__ ed_g)
{
    __shared__ ushort xs[16 * XSTR];   // 4.25 KB
    const int j    = threadIdx.x;
    const int w    = j >> 6, lane = j & 63, quad = lane >> 4, n16 = lane & 15;
    const int b    = blockIdx.x >> 6, mt16 = blockIdx.x & 63;
    const long rowbase = (long)b * Nsz + mt16 * 16;

    // B fragments from global Wt (L2-hot)
    short8 bfr[4][4];
    #pragma unroll
    for (int kk = 0; kk < 4; kk++)
        #pragma unroll
        for (int c4 = 0; c4 < 4; c4++)
            bfr[kk][c4] = *(const short8*)(Wt + (w*64 + c4*16 + n16) * FIN + kk*32 + quad*8);

    // stage x tile (16x128) as bf16 into LDS
    {
        const int r = j >> 4, k0 = (j & 15) * 8;
        const float4* g4 = (const float4*)(x + (rowbase + r) * FIN + k0);
        float4 v0 = g4[0], v1 = g4[1];
        ushort u[8] = { f2bf(v0.x), f2bf(v0.y), f2bf(v0.z), f2bf(v0.w),
                        f2bf(v1.x), f2bf(v1.y), f2bf(v1.z), f2bf(v1.w) };
        *(int4*)(xs + r * XSTR + k0) = *(int4*)u;
    }
    __syncthreads();

    f32x4 acc[4];
    #pragma unroll
    for (int c4 = 0; c4 < 4; c4++)
        #pragma unroll
        for (int r = 0; r < 4; r++) acc[c4][r] = 0.f;

    #pragma unroll
    for (int kk = 0; kk < 4; kk++) {
        short8 af = *(const short8*)(xs + n16 * XSTR + kk*32 + quad*8);
        #pragma unroll
        for (int c4 = 0; c4 < 4; c4++)
            acc[c4] = __builtin_amdgcn_mfma_f32_16x16x32_bf16(af, bfr[kk][c4], acc[c4], 0, 0, 0);
    }

    // ---- h_gB store: [b][mt=row/32][c][k=row%32] bf16 ----
    const int mtile = mt16 >> 1;
    const int kbase = (mt16 & 1) * 16 + quad * 4;
    #pragma unroll
    for (int c4 = 0; c4 < 4; c4++) {
        uint2 pk;
        pk.x = (uint)f2bf(acc[c4][0]) | ((uint)f2bf(acc[c4][1]) << 16);
        pk.y = (uint)f2bf(acc[c4][2]) | ((uint)f2bf(acc[c4][3]) << 16);
        const int c = w*64 + c4*16 + n16;
        *(uint2*)(h_gB + (((long)(b*32 + mtile) * COLS + c) * 32 + kbase)) = pk;
    }

    // ---- es/ed from fp32 accumulators ----
    float aS[4], aD[4];
    #pragma unroll
    for (int c4 = 0; c4 < 4; c4++) {
        aS[c4] = a[w * (2*FO) + c4*16 + n16];
        aD[c4] = a[w * (2*FO) + FO + c4*16 + n16];
    }
    #pragma unroll
    for (int reg = 0; reg < 4; reg++) {
        float ps = 0.f, pd = 0.f;
        #pragma unroll
        for (int c4 = 0; c4 < 4; c4++) {
            ps = fmaf(acc[c4][reg], aS[c4], ps);
            pd = fmaf(acc[c4][reg], aD[c4], pd);
        }
        #pragma unroll
        for (int off = 1; off < 16; off <<= 1) {
            ps += __shfl_xor(ps, off, 64);
            pd += __shfl_xor(pd, off, 64);
        }
        if (n16 == 0) {
            const long row = rowbase + quad*4 + reg;
            es_g[(long)w * BN + row] = ps * LOG2E - CSHIFT;   // shift folded into es
            ed_g[(long)w * BN + row] = pd * LOG2E;
        }
    }
}

// ---------------- Kernel B: barrier-free main loop ----------------
// grid (Bsz, Nsz/TN), 256 thr. Wave w = head w; lane (n16, quad) computes p for
// row n16, m in [8*quad, 8*quad+8) -- exactly the MFMA A-fragment layout, so p
// never touches LDS and the main loop has NO __syncthreads (no vmcnt drain).
// adj comes from the 1-bit mask (128 KB/batch, L2-resident); ed staged in LDS once.
// Denominator l = P x ones via one extra MFMA (lands in D-row layout, f32 accum
// of the same bf16 p's the numerator uses).
// NT = 32 m-tiles of TM=32 (round-2 bug: loop ran 64 tiles -> OOB h/edT/abT reads).
__global__ __launch_bounds__(256, 2) void gat_attn(
    const uint* __restrict__ ab, const ushort* __restrict__ h_gB,
    const float* __restrict__ es_g, const float* __restrict__ ed_g,
    float* __restrict__ out)
{
    __shared__ __align__(16) char smem[Hh * TN * 65 * 4];   // 16.64 KB: edT then o_lds (reused)
    __shared__ uint abT[TN][36];                            // 2.25 KB, 16B-aligned rows
    float (*edT)[Nsz]      = (float (*)[Nsz])smem;          // [Hh][Nsz] (16 KB)
    float (*o_lds)[TN][65] = (float (*)[TN][65])smem;       // [Hh][TN][65]

    const int j    = threadIdx.x;
    const int w    = j >> 6, lane = j & 63, quad = lane >> 4, n16 = lane & 15;
    const int b    = blockIdx.x, n0 = blockIdx.y * TN;      // linear%8 == b -> XCD k owns batch k
    const long rowb = (long)b * Nsz + n0;

    // stage edT[w][0..1023] (each wave stages its own head; coalesced float4)
    {
        const float* src = ed_g + (long)w * BN + (long)b * Nsz + lane * 16;
        float* dst = &edT[w][lane * 16];
        #pragma unroll
        for (int i = 0; i < 4; i++)
            *(float4*)(dst + i*4) = *(const float4*)(src + i*4);
    }
    // stage adj bits: 16 rows x 32 uints
    if (j < 128) {
        const int r = j >> 3, c = (j & 7) * 4;
        *(int4*)&abT[r][c] = *(const int4*)(ab + (rowb + r) * 32 + c);
    }
    const float esC = es_g[(long)w * BN + rowb + n16];      // pre-scaled, -CSHIFT folded
    __syncthreads();                                        // the ONLY pre-epilogue barrier

    f32x4 acc[4], accl;
    #pragma unroll
    for (int c4 = 0; c4 < 4; c4++)
        #pragma unroll
        for (int r = 0; r < 4; r++) acc[c4][r] = 0.f;
    #pragma unroll
    for (int r = 0; r < 4; r++) accl[r] = 0.f;

    short8 ones;
    #pragma unroll
    for (int i = 0; i < 8; i++) ones[i] = (short)0x3F80;    // bf16 1.0

    const ushort* hb = h_gB + (long)b * (Nsz * COLS);
    short8 h0[4], h1[4];

#define PRE_H(t, H) {                                                           \
    const ushort* hp = hb + (long)(t) * (COLS * TM);                            \
    _Pragma("unroll")                                                           \
    for (int c4 = 0; c4 < 4; c4++)                                              \
        H[c4] = *(const short8*)(hp + (w*64 + c4*16 + n16) * TM + quad*8); }

#define SUBT(t, HC, ABU) {                                                      \
    f32x4 ev0 = *(const f32x4*)&edT[w][(t)*32 + quad*8];                        \
    f32x4 ev1 = *(const f32x4*)&edT[w][(t)*32 + quad*8 + 4];                    \
    const uint b8 = ((ABU) >> (quad*8)) & 0xffu;                                \
    uint pk[4];                                                                 \
    _Pragma("unroll")                                                           \
    for (int p2 = 0; p2 < 4; p2++) {                                            \
        float t0 = esC + (p2 < 2 ? ev0[p2*2]     : ev1[(p2-2)*2]);              \
        float t1 = esC + (p2 < 2 ? ev0[p2*2 + 1] : ev1[(p2-2)*2 + 1]);          \
        float u0 = fmaxf(t0, fmaf(0.2f, t0, NEG08C));                           \
        float u1 = fmaxf(t1, fmaf(0.2f, t1, NEG08C));                           \
        float e0 = fexp2(u0), e1 = fexp2(u1);                                   \
        e0 = (b8 & (1u << (p2*2)))     ? e0 : 0.f;                              \
        e1 = (b8 & (1u << (p2*2 + 1))) ? e1 : 0.f;                              \
        asm("v_cvt_pk_bf16_f32 %0, %1, %2" : "=v"(pk[p2]) : "v"(e0), "v"(e1));  \
    }                                                                           \
    short8 af;                                                                  \
    ((uint*)&af)[0] = pk[0]; ((uint*)&af)[1] = pk[1];                           \
    ((uint*)&af)[2] = pk[2]; ((uint*)&af)[3] = pk[3];                           \
    accl = __builtin_amdgcn_mfma_f32_16x16x32_bf16(af, ones, accl, 0, 0, 0);    \
    _Pragma("unroll")                                                           \
    for (int c4 = 0; c4 < 4; c4++)                                              \
        acc[c4] = __builtin_amdgcn_mfma_f32_16x16x32_bf16(af, HC[c4], acc[c4], 0, 0, 0); }

    PRE_H(0, h0);
    uint4 abq = *(const uint4*)&abT[n16][0];
    for (int t4 = 0; t4 < NT; t4 += 4) {
        const int tn = (t4 + 4 < NT) ? t4 + 4 : 0;
        uint4 abn = *(const uint4*)&abT[n16][tn];            // next group's bits (clamped)
        PRE_H(t4 + 1, h1);  SUBT(t4,     h0, abq.x);
        PRE_H(t4 + 2, h0);  SUBT(t4 + 1, h1, abq.y);
        PRE_H(t4 + 3, h1);  SUBT(t4 + 2, h0, abq.z);
        if (t4 + 4 < NT) PRE_H(t4 + 4, h0);
        SUBT(t4 + 3, h1, abq.w);
        abq = abn;
    }

    // ---- epilogue: rinv from accl (already in D-row layout), mean over heads ----
    float rinv[4];
    #pragma unroll
    for (int reg = 0; reg < 4; reg++) rinv[reg] = 0.25f / accl[reg];

    __syncthreads();    // all waves done reading edT/abT; safe to overwrite as o_lds
    #pragma unroll
    for (int c4 = 0; c4 < 4; c4++)
        #pragma unroll
        for (int reg = 0; reg < 4; reg++)
            o_lds[w][quad*4 + reg][c4*16 + n16] = acc[c4][reg] * rinv[reg];
    __syncthreads();

    {
        const int f = j & 63, rb4 = j >> 6;
        #pragma unroll
        for (int i = 0; i < 4; i++) {
            const int r = i*4 + rb4;
            const float s = o_lds[0][r][f] + o_lds[1][r][f]
                          + o_lds[2][r][f] + o_lds[3][r][f];
            out[(rowb + r) * FO + f] = s;
        }
    }
#undef PRE_H
#undef SUBT
}

extern "C" void kernel_launch(void* const* d_in, const int* in_sizes, int n_in,
                              void* d_out, int out_size, void* d_ws, size_t ws_size,
                              hipStream_t stream) {
    const float* x   = (const float*)d_in[0];   // (8,1024,128) f32
    const int*   adj = (const int*)d_in[1];     // (8,1024,1024) i32
    const float* W   = (const float*)d_in[2];   // (128,256) f32
    const float* a   = (const float*)d_in[3];   // (4,128) f32
    float* out = (float*)d_out;                 // (8,1024,64) f32

    // ws: Wt bf16 (64KB) | h_gB bf16 (4MB) | es (128KB) | ed (128KB) | adjbits (1MB)
    ushort* Wt   = (ushort*)d_ws;
    ushort* h_gB = Wt + (size_t)COLS * FIN;
    float*  es_g = (float*)(h_gB + (size_t)BN * COLS);
    float*  ed_g = es_g + (size_t)Hh * BN;
    uint*   abb  = (uint*)(ed_g + (size_t)Hh * BN);

    gat_prep<<<dim3(1032),          dim3(256), 0, stream>>>(W, Wt, adj, abb);
    gat_proj<<<dim3(Bsz*Nsz/16),    dim3(256), 0, stream>>>(x, Wt, a, h_gB, es_g, ed_g);
    gat_attn<<<dim3(Bsz, Nsz/TN),   dim3(256), 0, stream>>>(abb, h_gB, es_g, ed_g, out);
}

// Round 4
// 108.289 us; speedup vs baseline: 1.0546x; 1.0125x over previous
//
#include <hip/hip_runtime.h>
#include <math.h>

#define Bsz 8
#define Nsz 1024
#define FIN 128
#define Hh  4
#define FO  64
#define COLS 256   // Hh*FO
#define TN  16
#define TM  32
#define NT  (Nsz/TM)   // 32 m-tiles
#define BN  (Bsz*Nsz)
#define XSTR 136   // ushort stride (128 data + 8 pad)
#define LOG2E  1.44269504088896340f
#define CSHIFT 17.3123404906675611f     // 12*log2(e): exp(s-12) == exp2(s*log2e - CSHIFT)
#define NEG08C (-0.8f * CSHIFT)         // leaky in t-domain: fma(0.2, t, -0.8C)

typedef __attribute__((ext_vector_type(8))) short short8;
typedef __attribute__((ext_vector_type(4))) float f32x4;

static __device__ inline ushort f2bf(float f) {           // RNE float->bf16
    uint u = __float_as_uint(f);
    u += 0x7FFFu + ((u >> 16) & 1u);
    return (ushort)(u >> 16);
}

static __device__ inline float fexp2(float x) {
#if __has_builtin(__builtin_amdgcn_exp2f)
    return __builtin_amdgcn_exp2f(x);
#else
    float r; asm("v_exp_f32 %0, %1" : "=v"(r) : "v"(x));
    return r;
#endif
}

// ---------------- Kernel A: h = x@W via MFMA; W converted in-block (no prep kernel) ----
// grid 512 = (b, 16-row tile), 256 thr. Wave w = head w (cols w*64..w*64+63).
// W (128KB f32, L2-hot after first blocks) is staged per-block into wLDS as bf16
// col-major-k (thread j owns column j; 128 coalesced dword loads, cvt_pk pairs,
// b128 LDS writes every 8 k's -> bounded liveness).
__global__ __launch_bounds__(256) void gat_proj(
    const float* __restrict__ x, const float* __restrict__ W,
    const float* __restrict__ a, ushort* __restrict__ h_gB,
    float* __restrict__ es_g, float* __restrict__ ed_g)
{
    __shared__ ushort xs[16 * XSTR];       // 4.25 KB
    __shared__ ushort wLDS[COLS * XSTR];   // 68 KB
    const int j    = threadIdx.x;
    const int w    = j >> 6, lane = j & 63, quad = lane >> 4, n16 = lane & 15;
    const int b    = blockIdx.x >> 6, mt16 = blockIdx.x & 63;
    const long rowbase = (long)b * Nsz + mt16 * 16;

    // stage x tile (16x128) as bf16 into LDS (HBM loads issued first)
    {
        const int r = j >> 4, k0 = (j & 15) * 8;
        const float4* g4 = (const float4*)(x + (rowbase + r) * FIN + k0);
        float4 v0 = g4[0], v1 = g4[1];
        ushort u[8] = { f2bf(v0.x), f2bf(v0.y), f2bf(v0.z), f2bf(v0.w),
                        f2bf(v1.x), f2bf(v1.y), f2bf(v1.z), f2bf(v1.w) };
        *(int4*)(xs + r * XSTR + k0) = *(int4*)u;
    }

    // stage W column j: wLDS[j][k] = bf16(W[k][j]), chunks of 8 k
    #pragma unroll
    for (int i8 = 0; i8 < 16; i8++) {
        float wv[8];
        #pragma unroll
        for (int ii = 0; ii < 8; ii++) wv[ii] = W[(i8*8 + ii) * COLS + j];
        uint pk4[4];
        #pragma unroll
        for (int i2 = 0; i2 < 4; i2++)
            asm("v_cvt_pk_bf16_f32 %0, %1, %2" : "=v"(pk4[i2]) : "v"(wv[2*i2]), "v"(wv[2*i2+1]));
        *(int4*)(wLDS + j * XSTR + i8*8) = *(int4*)pk4;
    }
    __syncthreads();

    // B fragments from wLDS (2-way bank aliasing on reads -> free)
    short8 bfr[4][4];
    #pragma unroll
    for (int kk = 0; kk < 4; kk++)
        #pragma unroll
        for (int c4 = 0; c4 < 4; c4++)
            bfr[kk][c4] = *(const short8*)(wLDS + (w*64 + c4*16 + n16) * XSTR + kk*32 + quad*8);

    f32x4 acc[4];
    #pragma unroll
    for (int c4 = 0; c4 < 4; c4++)
        #pragma unroll
        for (int r = 0; r < 4; r++) acc[c4][r] = 0.f;

    #pragma unroll
    for (int kk = 0; kk < 4; kk++) {
        short8 af = *(const short8*)(xs + n16 * XSTR + kk*32 + quad*8);
        #pragma unroll
        for (int c4 = 0; c4 < 4; c4++)
            acc[c4] = __builtin_amdgcn_mfma_f32_16x16x32_bf16(af, bfr[kk][c4], acc[c4], 0, 0, 0);
    }

    // ---- h_gB store: [b][mt=row/32][c][k=row%32] bf16 ----
    const int mtile = mt16 >> 1;
    const int kbase = (mt16 & 1) * 16 + quad * 4;
    #pragma unroll
    for (int c4 = 0; c4 < 4; c4++) {
        uint2 pk;
        pk.x = (uint)f2bf(acc[c4][0]) | ((uint)f2bf(acc[c4][1]) << 16);
        pk.y = (uint)f2bf(acc[c4][2]) | ((uint)f2bf(acc[c4][3]) << 16);
        const int c = w*64 + c4*16 + n16;
        *(uint2*)(h_gB + (((long)(b*32 + mtile) * COLS + c) * 32 + kbase)) = pk;
    }

    // ---- es/ed from fp32 accumulators (log2e-scaled; CSHIFT folded into es) ----
    float aS[4], aD[4];
    #pragma unroll
    for (int c4 = 0; c4 < 4; c4++) {
        aS[c4] = a[w * (2*FO) + c4*16 + n16];
        aD[c4] = a[w * (2*FO) + FO + c4*16 + n16];
    }
    #pragma unroll
    for (int reg = 0; reg < 4; reg++) {
        float ps = 0.f, pd = 0.f;
        #pragma unroll
        for (int c4 = 0; c4 < 4; c4++) {
            ps = fmaf(acc[c4][reg], aS[c4], ps);
            pd = fmaf(acc[c4][reg], aD[c4], pd);
        }
        #pragma unroll
        for (int off = 1; off < 16; off <<= 1) {
            ps += __shfl_xor(ps, off, 64);
            pd += __shfl_xor(pd, off, 64);
        }
        if (n16 == 0) {
            const long row = rowbase + quad*4 + reg;
            es_g[(long)w * BN + row] = ps * LOG2E - CSHIFT;
            ed_g[(long)w * BN + row] = pd * LOG2E;
        }
    }
}

// ---------------- Kernel B: barrier-free main loop, in-block m-split, self adj-pack ----
// grid (Bsz, Nsz/TN), 512 thr. Group g = j>>8 owns m-tiles [16g, 16g+16).
// Wave (g,w) = head w; lane (n16, quad) computes p for row n16, m in [8q, 8q+8)
// == MFMA A-fragment layout, so p stays in registers; main loop has NO barriers.
// adj packed in-block via __ballot (64 coalesced cols per wave-op) into abT.
// Denominator l = P x ones via one extra MFMA (D-row layout).
__global__ __launch_bounds__(512, 4) void gat_attn(
    const int* __restrict__ adj, const ushort* __restrict__ h_gB,
    const float* __restrict__ es_g, const float* __restrict__ ed_g,
    float* __restrict__ out)
{
    // phase1: edT [0,16K) + abT [16K,18.25K) ; phase2: merge [0,20K) + o_lds [20K,36.25K)
    __shared__ __align__(16) char smem[20*1024 + Hh * TN * 65 * 4];
    float (*edT)[Nsz]      = (float (*)[Nsz])smem;                   // [Hh][1024]
    uint  (*abT)[36]       = (uint (*)[36])(smem + 16*1024);         // [16][36]
    float (*o_lds)[TN][65] = (float (*)[TN][65])(smem + 20*1024);    // [Hh][16][65]

    const int j    = threadIdx.x;
    const int g    = j >> 8;                  // m-group
    const int jg   = j & 255;
    const int w    = jg >> 6, lane = jg & 63, quad = lane >> 4, n16 = lane & 15;
    const int b    = blockIdx.x, n0 = blockIdx.y * TN;   // linear%8==b -> XCD b owns batch b
    const long rowb = (long)b * Nsz + n0;

    // stage edT[w][g*512 .. g*512+512): each (g,w) wave stages the half it consumes
    {
        const float* src = ed_g + (long)w * BN + (long)b * Nsz + g*512 + lane*8;
        float* dst = &edT[w][g*512 + lane*8];
        *(float4*)dst       = *(const float4*)src;
        *(float4*)(dst + 4) = *(const float4*)(src + 4);
    }
    // ballot-pack adj: block reads its 16 rows (64KB, contiguous) -> 16x32 uints
    {
        const int* ap = adj + rowb * (long)Nsz;
        #pragma unroll 4
        for (int k = 0; k < 32; k++) {
            const int idx = k*512 + j;              // 0..16383
            const int v = ap[idx];
            const unsigned long long m = __ballot(v > 0);
            if (lane == 0) {
                const int row = idx >> 10, col0 = idx & 1023;   // col0 is 64-aligned
                *(uint2*)&abT[row][col0 >> 5] = make_uint2((uint)m, (uint)(m >> 32));
            }
        }
    }
    const float esC = es_g[(long)w * BN + rowb + n16];   // log2e-scaled, -CSHIFT folded
    __syncthreads();                                     // the ONLY pre-epilogue barrier

    f32x4 acc[4], accl;
    #pragma unroll
    for (int c4 = 0; c4 < 4; c4++)
        #pragma unroll
        for (int r = 0; r < 4; r++) acc[c4][r] = 0.f;
    #pragma unroll
    for (int r = 0; r < 4; r++) accl[r] = 0.f;

    short8 ones;
    #pragma unroll
    for (int i = 0; i < 8; i++) ones[i] = (short)0x3F80;    // bf16 1.0

    const ushort* hb = h_gB + (long)b * (Nsz * COLS);
    short8 h0[4], h1[4];

#define PRE_H(t, H) {                                                           \
    const ushort* hp = hb + (long)(t) * (COLS * TM);                            \
    _Pragma("unroll")                                                           \
    for (int c4 = 0; c4 < 4; c4++)                                              \
        H[c4] = *(const short8*)(hp + (w*64 + c4*16 + n16) * TM + quad*8); }

#define SUBT(t, HC, ABU) {                                                      \
    f32x4 ev0 = *(const f32x4*)&edT[w][(t)*32 + quad*8];                        \
    f32x4 ev1 = *(const f32x4*)&edT[w][(t)*32 + quad*8 + 4];                    \
    const uint b8 = ((ABU) >> (quad*8)) & 0xffu;                                \
    uint pk[4];                                                                 \
    _Pragma("unroll")                                                           \
    for (int p2 = 0; p2 < 4; p2++) {                                            \
        float t0 = esC + (p2 < 2 ? ev0[p2*2]     : ev1[(p2-2)*2]);              \
        float t1 = esC + (p2 < 2 ? ev0[p2*2 + 1] : ev1[(p2-2)*2 + 1]);          \
        float u0 = fmaxf(t0, fmaf(0.2f, t0, NEG08C));                           \
        float u1 = fmaxf(t1, fmaf(0.2f, t1, NEG08C));                           \
        float e0 = fexp2(u0), e1 = fexp2(u1);                                   \
        e0 = (b8 & (1u << (p2*2)))     ? e0 : 0.f;                              \
        e1 = (b8 & (1u << (p2*2 + 1))) ? e1 : 0.f;                              \
        asm("v_cvt_pk_bf16_f32 %0, %1, %2" : "=v"(pk[p2]) : "v"(e0), "v"(e1));  \
    }                                                                           \
    short8 af;                                                                  \
    ((uint*)&af)[0] = pk[0]; ((uint*)&af)[1] = pk[1];                           \
    ((uint*)&af)[2] = pk[2]; ((uint*)&af)[3] = pk[3];                           \
    accl = __builtin_amdgcn_mfma_f32_16x16x32_bf16(af, ones, accl, 0, 0, 0);    \
    _Pragma("unroll")                                                           \
    for (int c4 = 0; c4 < 4; c4++)                                              \
        acc[c4] = __builtin_amdgcn_mfma_f32_16x16x32_bf16(af, HC[c4], acc[c4], 0, 0, 0); }

    PRE_H(g*16, h0);
    uint4 abq = *(const uint4*)&abT[n16][g*16];
    for (int t4i = 0; t4i < 16; t4i += 4) {
        const int t4 = g*16 + t4i;
        const int tn = (t4i + 4 < 16) ? (t4 + 4) : g*16;
        uint4 abn = *(const uint4*)&abT[n16][tn];        // next group's bits (clamped)
        PRE_H(t4 + 1, h1);  SUBT(t4,     h0, abq.x);
        PRE_H(t4 + 2, h0);  SUBT(t4 + 1, h1, abq.y);
        PRE_H(t4 + 3, h1);  SUBT(t4 + 2, h0, abq.z);
        if (t4i + 4 < 16) PRE_H(t4 + 4, h0);
        SUBT(t4 + 3, h1, abq.w);
        abq = abn;
    }

    // ---- epilogue: merge m-groups, normalize, mean over heads ----
    __syncthreads();                      // all abT/edT reads done; reuse smem as merge buf
    float* mg = (float*)smem;             // [20][256]
    if (g == 1) {
        #pragma unroll
        for (int c4 = 0; c4 < 4; c4++)
            #pragma unroll
            for (int r = 0; r < 4; r++) mg[(c4*4 + r) * 256 + jg] = acc[c4][r];
        #pragma unroll
        for (int r = 0; r < 4; r++) mg[(16 + r) * 256 + jg] = accl[r];
    }
    __syncthreads();
    if (g == 0) {
        float rinv[4];
        #pragma unroll
        for (int r = 0; r < 4; r++)
            rinv[r] = 0.25f / (accl[r] + mg[(16 + r) * 256 + jg]);
        #pragma unroll
        for (int c4 = 0; c4 < 4; c4++)
            #pragma unroll
            for (int r = 0; r < 4; r++)
                o_lds[w][quad*4 + r][c4*16 + n16] =
                    (acc[c4][r] + mg[(c4*4 + r) * 256 + jg]) * rinv[r];
    }
    __syncthreads();

    {
        const int f = j & 63, r2 = (j >> 6) & 7;
        #pragma unroll
        for (int i = 0; i < 2; i++) {
            const int r = i*8 + r2;
            const float s = o_lds[0][r][f] + o_lds[1][r][f]
                          + o_lds[2][r][f] + o_lds[3][r][f];
            out[(rowb + r) * FO + f] = s;
        }
    }
#undef PRE_H
#undef SUBT
}

extern "C" void kernel_launch(void* const* d_in, const int* in_sizes, int n_in,
                              void* d_out, int out_size, void* d_ws, size_t ws_size,
                              hipStream_t stream) {
    const float* x   = (const float*)d_in[0];   // (8,1024,128) f32
    const int*   adj = (const int*)d_in[1];     // (8,1024,1024) i32
    const float* W   = (const float*)d_in[2];   // (128,256) f32
    const float* a   = (const float*)d_in[3];   // (4,128) f32
    float* out = (float*)d_out;                 // (8,1024,64) f32

    // ws: h_gB bf16 (4MB) | es (128KB) | ed (128KB)
    ushort* h_gB = (ushort*)d_ws;
    float*  es_g = (float*)(h_gB + (size_t)BN * COLS);
    float*  ed_g = es_g + (size_t)Hh * BN;

    gat_proj<<<dim3(Bsz*Nsz/16),  dim3(256), 0, stream>>>(x, W, a, h_gB, es_g, ed_g);
    gat_attn<<<dim3(Bsz, Nsz/TN), dim3(512), 0, stream>>>(adj, h_gB, es_g, ed_g, out);
}